// Round 2
// baseline (8258.569 us; speedup 1.0000x reference)
//
#include <hip/hip_runtime.h>
#include <math.h>

#define NTOK 65536
#define CDIM 96
#define BDIM 4

// ---------------- LayerNorm (wave per row) — used for LN2 per batch ----------------
__global__ __launch_bounds__(256) void ln_kernel(const float* __restrict__ x,
    const float* __restrict__ w, const float* __restrict__ b,
    float* __restrict__ out, int rows)
{
    int row = blockIdx.x * 4 + (threadIdx.x >> 6);
    int lane = threadIdx.x & 63;
    if (row >= rows) return;
    const float* xr = x + (size_t)row * CDIM;
    float v0 = xr[lane];
    float v1 = (lane < 32) ? xr[64 + lane] : 0.f;
    float s = v0 + v1, s2 = v0 * v0 + v1 * v1;
    #pragma unroll
    for (int off = 32; off; off >>= 1) { s += __shfl_down(s, off); s2 += __shfl_down(s2, off); }
    s = __shfl(s, 0); s2 = __shfl(s2, 0);
    float mu = s * (1.f / 96.f);
    float var = s2 * (1.f / 96.f) - mu * mu;
    float inv = rsqrtf(var + 1e-5f);
    float* orow = out + (size_t)row * CDIM;
    orow[lane] = (v0 - mu) * inv * w[lane] + b[lane];
    if (lane < 32) orow[64 + lane] = (v1 - mu) * inv * w[64 + lane] + b[64 + lane];
}

// ---------------- SPA: fused LN1 + window attention, one block per 8x8 window ----------------
__global__ __launch_bounds__(256) void spa_kernel(
    const float* __restrict__ x,
    const float* __restrict__ n1w, const float* __restrict__ n1b,
    const float* __restrict__ qw, const float* __restrict__ qb,
    const float* __restrict__ kvw, const float* __restrict__ kvb,
    const float* __restrict__ pw, const float* __restrict__ pb,
    const float* __restrict__ rpb, float* __restrict__ out)
{
    __shared__ float bufA[6144];   // xw tile, later reused as scores [6][64][16]
    __shared__ float qs[64][96];   // q, later per-head outputs
    __shared__ float kvs[64][48];
    __shared__ float rb[294];      // 49 x 6

    const int wi = blockIdx.x;
    const int b  = wi >> 10;
    const int wr = (wi >> 5) & 31;
    const int wc = wi & 31;
    const int t  = threadIdx.x;

    for (int i = t; i < 294; i += 256) rb[i] = rpb[i];

    const float* xb = x + (size_t)b * NTOK * CDIM;
    for (int i = t; i < 64 * 96; i += 256) {
        int r = i / 96, ch = i % 96;
        int gr = wr * 8 + (r >> 3), gc = wc * 8 + (r & 7);
        bufA[i] = xb[(size_t)(gr * 256 + gc) * CDIM + ch];
    }
    __syncthreads();

    // fused LN1 per row (64 threads, one row each)
    if (t < 64) {
        float s = 0.f, s2 = 0.f;
        for (int k = 0; k < 96; k++) { float v = bufA[t * 96 + k]; s += v; s2 += v * v; }
        float mu = s * (1.f / 96.f);
        float var = s2 * (1.f / 96.f) - mu * mu;
        float inv = rsqrtf(var + 1e-5f);
        for (int k = 0; k < 96; k++)
            bufA[t * 96 + k] = (bufA[t * 96 + k] - mu) * inv * n1w[k] + n1b[k];
    }
    __syncthreads();

    // q = (xw @ qw + qb) * 0.25
    for (int i = t; i < 64 * 96; i += 256) {
        int r = i / 96, j = i % 96;
        float acc = qb[j];
        for (int k = 0; k < 96; k++) acc += bufA[r * 96 + k] * qw[k * 96 + j];
        qs[r][j] = acc * 0.25f;
    }
    // kv = xw @ kvw + kvb
    for (int i = t; i < 64 * 48; i += 256) {
        int r = i / 48, j = i % 48;
        float acc = kvb[j];
        for (int k = 0; k < 96; k++) acc += bufA[r * 96 + k] * kvw[k * 48 + j];
        kvs[r][j] = acc;
    }
    __syncthreads();

    // scores: sc[h][r][p] overwrites bufA (reads only qs/kvs here)
    for (int i = t; i < 6 * 64 * 16; i += 256) {
        int h = i >> 10, r = (i >> 4) & 63, p = i & 15;
        int pi = p >> 2, pj = p & 3;
        float acc = 0.f;
        #pragma unroll
        for (int d = 0; d < 16; d++) {
            int f = h * 16 + d;
            int i2 = (f >= 48) ? 1 : 0;
            int j2 = (f / 24) & 1;
            int cc = f % 24;
            int nn = (pi * 2 + i2) * 8 + (pj * 2 + j2);
            acc += qs[r][f] * kvs[nn][cc];
        }
        int qi = (r >> 3) >> 1, qj = (r & 7) >> 1;
        int bi = (qi - pi + 3) * 7 + (qj - pj + 3);
        bufA[(h * 64 + r) * 16 + p] = acc + rb[bi * 6 + h];
    }
    __syncthreads();

    // softmax over p=16 per (h,r)
    for (int i = t; i < 6 * 64; i += 256) {
        float* row = &bufA[i * 16];
        float m = -1e30f;
        #pragma unroll
        for (int p = 0; p < 16; p++) m = fmaxf(m, row[p]);
        float s = 0.f;
        #pragma unroll
        for (int p = 0; p < 16; p++) { float e = __expf(row[p] - m); row[p] = e; s += e; }
        float inv = 1.f / s;
        #pragma unroll
        for (int p = 0; p < 16; p++) row[p] *= inv;
    }
    __syncthreads();

    // out-heads: o[r][f] = sum_p attn[h][r][p] * v  (overwrites qs)
    for (int i = t; i < 64 * 96; i += 256) {
        int r = i / 96, f = i % 96;
        int h = f >> 4;
        int i2 = (f >= 48) ? 1 : 0;
        int j2 = (f / 24) & 1;
        int cc = f % 24;
        float acc = 0.f;
        #pragma unroll
        for (int p = 0; p < 16; p++) {
            int pi = p >> 2, pj = p & 3;
            int nn = (pi * 2 + i2) * 8 + (pj * 2 + j2);
            acc += bufA[(h * 64 + r) * 16 + p] * kvs[nn][24 + cc];
        }
        qs[r][f] = acc;
    }
    __syncthreads();

    // final projection + residual:  out = x + o @ pw + pb
    float* ob = out + (size_t)b * NTOK * CDIM;
    for (int i = t; i < 64 * 96; i += 256) {
        int r = i / 96, j = i % 96;
        float acc = pb[j];
        for (int k = 0; k < 96; k++) acc += qs[r][k] * pw[k * 96 + j];
        int gr = wr * 8 + (r >> 3), gc = wc * 8 + (r & 7);
        size_t gi = (size_t)(gr * 256 + gc) * CDIM + j;
        ob[gi] = xb[gi] + acc;
    }
}

// ---------------- (N x 96) @ (96 x 96), fused LN on input ----------------
__global__ __launch_bounds__(256) void proj96ln_kernel(const float* __restrict__ in,
    const float* __restrict__ lnw, const float* __restrict__ lnb,
    const float* __restrict__ w, float* __restrict__ out)
{
    __shared__ float xs[64][96];
    __shared__ float ws[96 * 96];
    int r0 = blockIdx.x * 64;
    int t = threadIdx.x;
    for (int i = t; i < 64 * 96; i += 256) { int r = i / 96, ch = i % 96; xs[r][ch] = in[(size_t)(r0 + r) * 96 + ch]; }
    for (int i = t; i < 96 * 96; i += 256) ws[i] = w[i];
    __syncthreads();
    if (t < 64) {
        float s = 0.f, s2 = 0.f;
        for (int k = 0; k < 96; k++) { float v = xs[t][k]; s += v; s2 += v * v; }
        float mu = s * (1.f / 96.f);
        float var = s2 * (1.f / 96.f) - mu * mu;
        float inv = rsqrtf(var + 1e-5f);
        for (int k = 0; k < 96; k++) xs[t][k] = (xs[t][k] - mu) * inv * lnw[k] + lnb[k];
    }
    __syncthreads();
    for (int i = t; i < 64 * 96; i += 256) {
        int r = i / 96, j = i % 96;
        float acc = 0.f;
        for (int k = 0; k < 96; k++) acc += xs[r][k] * ws[k * 96 + j];
        out[(size_t)(r0 + r) * 96 + j] = acc;
    }
}

// kv projection with fused LN, split into contiguous k (N,48) and v (N,48)
__global__ __launch_bounds__(256) void projkvln_kernel(const float* __restrict__ in,
    const float* __restrict__ lnw, const float* __restrict__ lnb,
    const float* __restrict__ w, float* __restrict__ kout, float* __restrict__ vout)
{
    __shared__ float xs[64][96];
    __shared__ float ws[96 * 96];
    int r0 = blockIdx.x * 64;
    int t = threadIdx.x;
    for (int i = t; i < 64 * 96; i += 256) { int r = i / 96, ch = i % 96; xs[r][ch] = in[(size_t)(r0 + r) * 96 + ch]; }
    for (int i = t; i < 96 * 96; i += 256) ws[i] = w[i];
    __syncthreads();
    if (t < 64) {
        float s = 0.f, s2 = 0.f;
        for (int k = 0; k < 96; k++) { float v = xs[t][k]; s += v; s2 += v * v; }
        float mu = s * (1.f / 96.f);
        float var = s2 * (1.f / 96.f) - mu * mu;
        float inv = rsqrtf(var + 1e-5f);
        for (int k = 0; k < 96; k++) xs[t][k] = (xs[t][k] - mu) * inv * lnw[k] + lnb[k];
    }
    __syncthreads();
    for (int i = t; i < 64 * 96; i += 256) {
        int r = i / 96, j = i % 96;
        float acc = 0.f;
        for (int k = 0; k < 96; k++) acc += xs[r][k] * ws[k * 96 + j];
        if (j < 48) kout[(size_t)(r0 + r) * 48 + j] = acc;
        else        vout[(size_t)(r0 + r) * 48 + (j - 48)] = acc;
    }
}

// (N x 96) @ (96 x 96) accumulated into out
__global__ __launch_bounds__(256) void proj96_add_kernel(const float* __restrict__ in,
    const float* __restrict__ w, float* __restrict__ out)
{
    __shared__ float xs[64][96];
    __shared__ float ws[96 * 96];
    int r0 = blockIdx.x * 64;
    int t = threadIdx.x;
    for (int i = t; i < 64 * 96; i += 256) { int r = i / 96, ch = i % 96; xs[r][ch] = in[(size_t)(r0 + r) * 96 + ch]; }
    for (int i = t; i < 96 * 96; i += 256) ws[i] = w[i];
    __syncthreads();
    for (int i = t; i < 64 * 96; i += 256) {
        int r = i / 96, j = i % 96;
        float acc = 0.f;
        for (int k = 0; k < 96; k++) acc += xs[r][k] * ws[k * 96 + j];
        out[(size_t)(r0 + r) * 96 + j] += acc;
    }
}

__global__ void zero_kernel(float* p, int n)
{
    int i = blockIdx.x * blockDim.x + threadIdx.x;
    if (i < n) p[i] = 0.f;
}

// ---------------- SCA (per batch): K^T Q contraction over n ----------------
#define NCH 64
__global__ __launch_bounds__(256) void sca_attn_kernel(const float* __restrict__ qp,
    const float* __restrict__ kbuf, float* __restrict__ attnbuf)
{
    int blk = blockIdx.x;
    int ch = blk % NCH;
    int h  = blk / NCH;
    const float* qbase = qp   + (size_t)(h * 16) * NTOK;
    const float* kbase = kbuf + (size_t)(h * 8) * NTOK;

    float acc[8][16];
    #pragma unroll
    for (int kk = 0; kk < 8; kk++)
        #pragma unroll
        for (int qq = 0; qq < 16; qq++) acc[kk][qq] = 0.f;

    const int span = NTOK / NCH;
    int n0 = ch * span;
    for (int n = n0 + threadIdx.x; n < n0 + span; n += 256) {
        float qv[16]; float qsum = 0.f;
        #pragma unroll
        for (int d = 0; d < 16; d++) { qv[d] = qbase[(size_t)d * NTOK + n]; qsum += qv[d] * qv[d]; }
        float qinv = 1.f / fmaxf(sqrtf(qsum), 1e-12f);
        float kv[8]; float ksum = 0.f;
        #pragma unroll
        for (int d = 0; d < 8; d++) { kv[d] = kbase[(size_t)d * NTOK + n]; ksum += kv[d] * kv[d]; }
        float kinv = 1.f / fmaxf(sqrtf(ksum), 1e-12f);
        #pragma unroll
        for (int d = 0; d < 16; d++) qv[d] *= qinv;
        #pragma unroll
        for (int d = 0; d < 8; d++) kv[d] *= kinv;
        #pragma unroll
        for (int kk = 0; kk < 8; kk++)
            #pragma unroll
            for (int qq = 0; qq < 16; qq++) acc[kk][qq] += kv[kk] * qv[qq];
    }
    int lane = threadIdx.x & 63;
    #pragma unroll
    for (int kk = 0; kk < 8; kk++) {
        #pragma unroll
        for (int qq = 0; qq < 16; qq++) {
            float v = acc[kk][qq];
            #pragma unroll
            for (int off = 32; off; off >>= 1) v += __shfl_down(v, off);
            if (lane == 0) atomicAdd(&attnbuf[(h * 8 + kk) * 16 + qq], v);
        }
    }
}

__global__ void sca_softmax_kernel(float* __restrict__ attnbuf)
{
    int i = threadIdx.x;
    if (i < 48) {
        float* row = attnbuf + i * 16;
        float m = -1e30f;
        #pragma unroll
        for (int q = 0; q < 16; q++) m = fmaxf(m, row[q]);
        float s = 0.f;
        #pragma unroll
        for (int q = 0; q < 16; q++) { float e = __expf(row[q] - m); row[q] = e; s += e; }
        float inv = 1.f / s;
        #pragma unroll
        for (int q = 0; q < 16; q++) row[q] *= inv;
    }
}

#define NCH2 64
__global__ __launch_bounds__(256) void sca_out_kernel(const float* __restrict__ vbuf,
    const float* __restrict__ attnbuf, float* __restrict__ scao)
{
    int blk = blockIdx.x;
    int ch = blk % NCH2;
    int h  = blk / NCH2;
    __shared__ float at[128];
    int t = threadIdx.x;
    if (t < 128) at[t] = attnbuf[h * 128 + t];
    __syncthreads();
    const float* vbase = vbuf + (size_t)(h * 8) * NTOK;
    float*       obase = scao + (size_t)h * NTOK * 16;
    const int span = NTOK / NCH2;
    int n0 = ch * span;
    for (int n = n0 + t; n < n0 + span; n += 256) {
        float vv[8]; float vsum = 0.f;
        #pragma unroll
        for (int d = 0; d < 8; d++) { vv[d] = vbase[(size_t)d * NTOK + n]; vsum += vv[d] * vv[d]; }
        float vinv = 1.f / fmaxf(sqrtf(vsum), 1e-12f);
        #pragma unroll
        for (int q = 0; q < 16; q++) {
            float a = 0.f;
            #pragma unroll
            for (int kk = 0; kk < 8; kk++) a += vv[kk] * at[kk * 16 + q];
            obase[(size_t)n * 16 + q] = a * vinv;
        }
    }
}

// ---------------- FFN (per batch, per 64-channel chunk) ----------------
// fc1: (N x 96) @ (96 x [64 cols @ wcol0]) + b  -> dst (N,64)
__global__ __launch_bounds__(256) void fc1_kernel(const float* __restrict__ in,
    const float* __restrict__ w, const float* __restrict__ bias,
    float* __restrict__ dst, int wcol0)
{
    __shared__ float xs[64][96];
    __shared__ float wt[96][64];
    int r0 = blockIdx.x * 64;
    int t = threadIdx.x;
    for (int i = t; i < 64 * 96; i += 256) { int r = i / 96, ch = i % 96; xs[r][ch] = in[(size_t)(r0 + r) * 96 + ch]; }
    for (int i = t; i < 96 * 64; i += 256) { int k = i >> 6, j = i & 63; wt[k][j] = w[(size_t)k * 512 + wcol0 + j]; }
    __syncthreads();
    for (int i = t; i < 64 * 64; i += 256) {
        int r = i >> 6, j = i & 63;
        float acc = bias[wcol0 + j];
        for (int k = 0; k < 96; k++) acc += xs[r][k] * wt[k][j];
        dst[(size_t)(r0 + r) * 64 + j] = acc;
    }
}

// depthwise 3x3 SAME + bias, exact gelu, * gate; chunk of 64 channels; c aliases g
__global__ __launch_bounds__(256) void dwconv_kernel(const float* __restrict__ a,
    const float* __restrict__ g, const float* __restrict__ w,
    const float* __restrict__ bias, float* __restrict__ c, int ch0)
{
    int pix = blockIdx.x * 4 + (threadIdx.x >> 6);
    int r = pix >> 8, col = pix & 255;
    int ch = threadIdx.x & 63;
    float wv[9];
    #pragma unroll
    for (int i = 0; i < 9; i++) wv[i] = w[(ch0 + ch) * 9 + i];
    float acc = bias[ch0 + ch];
    #pragma unroll
    for (int dr = -1; dr <= 1; dr++) {
        int rr = r + dr;
        if (rr < 0 || rr > 255) continue;
        #pragma unroll
        for (int dc = -1; dc <= 1; dc++) {
            int cc = col + dc;
            if (cc < 0 || cc > 255) continue;
            acc += a[(size_t)(rr * 256 + cc) * 64 + ch] * wv[(dr + 1) * 3 + (dc + 1)];
        }
    }
    float xg = acc;
    float ge = 0.5f * xg * (1.f + erff(xg * 0.70710678118f));
    c[(size_t)pix * 64 + ch] = ge * g[(size_t)pix * 64 + ch];
}

// fc2 chunk: (N x 64) @ (64 rows @ ch0 of (256 x 96)) accumulated into out (+bias on chunk 0)
__global__ __launch_bounds__(256) void fc2_kernel(const float* __restrict__ in,
    const float* __restrict__ w, const float* __restrict__ bias,
    float* __restrict__ out, int ch0)
{
    __shared__ float xs[64][64];
    int r0 = blockIdx.x * 64;
    int t = threadIdx.x;
    for (int i = t; i < 64 * 64; i += 256) { int r = i >> 6, k = i & 63; xs[r][k] = in[(size_t)(r0 + r) * 64 + k]; }
    __syncthreads();
    for (int i = t; i < 64 * 96; i += 256) {
        int r = i / 96, j = i % 96;
        float acc = (ch0 == 0) ? bias[j] : 0.f;
        for (int k = 0; k < 64; k++) acc += xs[r][k] * w[(size_t)(ch0 + k) * 96 + j];
        out[(size_t)(r0 + r) * 96 + j] += acc;
    }
}

extern "C" void kernel_launch(void* const* d_in, const int* in_sizes, int n_in,
                              void* d_out, int out_size, void* d_ws, size_t ws_size,
                              hipStream_t stream)
{
    (void)in_sizes; (void)n_in; (void)out_size; (void)ws_size;
    const float* x       = (const float*)d_in[0];
    const float* n1w     = (const float*)d_in[1];
    const float* n1b     = (const float*)d_in[2];
    const float* spa_qw  = (const float*)d_in[3];
    const float* spa_qb  = (const float*)d_in[4];
    const float* spa_kvw = (const float*)d_in[5];
    const float* spa_kvb = (const float*)d_in[6];
    const float* spa_pw  = (const float*)d_in[7];
    const float* spa_pb  = (const float*)d_in[8];
    const float* rpb     = (const float*)d_in[9];
    const float* sca_qw  = (const float*)d_in[10];
    const float* sca_kvw = (const float*)d_in[11];
    const float* sca_pw  = (const float*)d_in[12];
    const float* n2w     = (const float*)d_in[13];
    const float* n2b     = (const float*)d_in[14];
    const float* fc1_w   = (const float*)d_in[15];
    const float* fc1_b   = (const float*)d_in[16];
    const float* dw_w    = (const float*)d_in[17];
    const float* dw_b    = (const float*)d_in[18];
    const float* fc2_w   = (const float*)d_in[19];
    const float* fc2_b   = (const float*)d_in[20];

    float* out = (float*)d_out;
    float* ws  = (float*)d_ws;

    const size_t NQP = (size_t)NTOK * 96;   // 6,291,456 floats
    const size_t NKV = (size_t)NTOK * 48;   // 3,145,728
    const size_t NH  = (size_t)NTOK * 64;   // 4,194,304

    // 1. SPA fused (writes out = x + spa), all batches
    spa_kernel<<<4096, 256, 0, stream>>>(x, n1w, n1b, spa_qw, spa_qb, spa_kvw, spa_kvb,
                                         spa_pw, spa_pb, rpb, out);

    // 2. SCA per batch (ws: qp | kb | vb | attn ; scao aliases qp)
    for (int b = 0; b < BDIM; b++) {
        const float* xb  = x   + (size_t)b * NQP;
        float*       ob  = out + (size_t)b * NQP;
        float* qp   = ws;
        float* kb   = ws + NQP;
        float* vb   = kb + NKV;
        float* attn = vb + NKV;
        float* scao = qp;  // alias: qp dead after sca_attn
        proj96ln_kernel<<<NTOK / 64, 256, 0, stream>>>(xb, n1w, n1b, sca_qw, qp);
        projkvln_kernel<<<NTOK / 64, 256, 0, stream>>>(xb, n1w, n1b, sca_kvw, kb, vb);
        zero_kernel<<<3, 256, 0, stream>>>(attn, 768);
        sca_attn_kernel<<<6 * NCH, 256, 0, stream>>>(qp, kb, attn);
        sca_softmax_kernel<<<1, 64, 0, stream>>>(attn);
        sca_out_kernel<<<6 * NCH2, 256, 0, stream>>>(vb, attn, scao);
        proj96_add_kernel<<<NTOK / 64, 256, 0, stream>>>(scao, sca_pw, ob);
    }

    // 3. FFN per batch, per 64-channel chunk (ws: xn2 | a | g ; c aliases g)
    for (int b = 0; b < BDIM; b++) {
        float* ob  = out + (size_t)b * NQP;
        float* xn2 = ws;
        float* ab  = ws + NQP;
        float* gb  = ab + NH;
        ln_kernel<<<NTOK / 4, 256, 0, stream>>>(ob, n2w, n2b, xn2, NTOK);
        for (int ch0 = 0; ch0 < 256; ch0 += 64) {
            fc1_kernel<<<NTOK / 64, 256, 0, stream>>>(xn2, fc1_w, fc1_b, ab, ch0);
            fc1_kernel<<<NTOK / 64, 256, 0, stream>>>(xn2, fc1_w, fc1_b, gb, 256 + ch0);
            dwconv_kernel<<<NTOK / 4, 256, 0, stream>>>(ab, gb, dw_w, dw_b, gb, ch0);
            fc2_kernel<<<NTOK / 64, 256, 0, stream>>>(gb, fc2_w, fc2_b, ob, ch0);
        }
    }
}

// Round 3
// 3061.674 us; speedup vs baseline: 2.6974x; 2.6974x over previous
//
#include <hip/hip_runtime.h>
#include <math.h>

#define NTOK 65536
#define BDIM 4

typedef __attribute__((ext_vector_type(8))) short bf16x8;
typedef __attribute__((ext_vector_type(4))) float f32x4;

__device__ __forceinline__ short f2b(float x) {
    union { float f; unsigned u; } v; v.f = x;
    unsigned r = v.u + 0x7fffu + ((v.u >> 16) & 1u);
    return (short)(r >> 16);
}

// ---------------- LayerNorm (wave per row) ----------------
__global__ __launch_bounds__(256) void ln_kernel(const float* __restrict__ x,
    const float* __restrict__ w, const float* __restrict__ b,
    float* __restrict__ out, int rows)
{
    int row = blockIdx.x * 4 + (threadIdx.x >> 6);
    int lane = threadIdx.x & 63;
    if (row >= rows) return;
    const float* xr = x + (size_t)row * 96;
    float v0 = xr[lane];
    float v1 = (lane < 32) ? xr[64 + lane] : 0.f;
    float s = v0 + v1, s2 = v0 * v0 + v1 * v1;
    #pragma unroll
    for (int off = 32; off; off >>= 1) { s += __shfl_down(s, off); s2 += __shfl_down(s2, off); }
    s = __shfl(s, 0); s2 = __shfl(s2, 0);
    float mu = s * (1.f / 96.f);
    float var = s2 * (1.f / 96.f) - mu * mu;
    float inv = rsqrtf(var + 1e-5f);
    float* orow = out + (size_t)row * 96;
    orow[lane] = (v0 - mu) * inv * w[lane] + b[lane];
    if (lane < 32) orow[64 + lane] = (v1 - mu) * inv * w[64 + lane] + b[64 + lane];
}

// ---------------- MFMA GEMM: C[64 x NT*16] = A[64 x K] @ W[K x NT*16] ----------------
// A fp32 row-major (lda == K), W fp32 row-major with ldw, slice at (wrow0, wcol0).
// Epilogue: +bias, *scale, +res (ld 96), accumulate, split cols>=48 -> dst2.
template<int NT, int KT>
__global__ __launch_bounds__(256) void gemm_kernel(
    const float* __restrict__ A,
    const float* __restrict__ W, int ldw, int wrow0, int wcol0,
    const float* __restrict__ bias, float scale,
    const float* __restrict__ res,
    float* __restrict__ dst, int ldd, float* __restrict__ dst2, int accum)
{
    constexpr int K = KT * 32;
    constexpr int AS = K + 8;              // bf16 stride (keeps 16B alignment, breaks bank aliasing)
    __shared__ short As[64 * AS];
    __shared__ short Ws[NT * 16 * AS];
    const int t = threadIdx.x;
    const size_t n0 = (size_t)blockIdx.x * 64;

    for (int i = t; i < 64 * (K / 4); i += 256) {
        int row = i / (K / 4), c4 = i % (K / 4);
        float4 v = *(const float4*)&A[(n0 + row) * K + c4 * 4];
        short4 s = { f2b(v.x), f2b(v.y), f2b(v.z), f2b(v.w) };
        *(short4*)&As[row * AS + c4 * 4] = s;
    }
    for (int i = t; i < NT * 16 * K; i += 256) {
        int k = i / (NT * 16), j = i % (NT * 16);
        Ws[j * AS + k] = f2b(W[(size_t)(wrow0 + k) * ldw + wcol0 + j]);
    }
    __syncthreads();

    const int l = t & 63, wv = t >> 6;
    const int lr = l & 15, lg = l >> 4;

    bf16x8 a[KT];
    #pragma unroll
    for (int kk = 0; kk < KT; kk++)
        a[kk] = *(const bf16x8*)&As[(wv * 16 + lr) * AS + kk * 32 + lg * 8];

    f32x4 acc[NT];
    #pragma unroll
    for (int nt = 0; nt < NT; nt++) acc[nt] = (f32x4){0.f, 0.f, 0.f, 0.f};

    #pragma unroll
    for (int nt = 0; nt < NT; nt++) {
        #pragma unroll
        for (int kk = 0; kk < KT; kk++) {
            bf16x8 b = *(const bf16x8*)&Ws[(nt * 16 + lr) * AS + kk * 32 + lg * 8];
            acc[nt] = __builtin_amdgcn_mfma_f32_16x16x32_bf16(a[kk], b, acc[nt], 0, 0, 0);
        }
    }

    #pragma unroll
    for (int nt = 0; nt < NT; nt++) {
        int col = nt * 16 + lr;
        float bv = bias ? bias[col] : 0.f;
        float* dp = dst; int cc = col;
        if (dst2 && col >= 48) { dp = dst2; cc = col - 48; }
        #pragma unroll
        for (int i = 0; i < 4; i++) {
            size_t row = n0 + wv * 16 + lg * 4 + i;
            float v = (acc[nt][i] + bv) * scale;
            if (res) v += res[row * 96 + col];
            size_t off = row * (size_t)ldd + cc;
            if (accum) v += dp[off];
            dp[off] = v;
        }
    }
}

// ---------------- SPA core: scores + softmax + PV per 8x8 window ----------------
// q (N,96), kv (N,48) precomputed; att may alias qbuf (block reads/writes only its own rows).
__global__ __launch_bounds__(256) void spa_core_kernel(
    const float* __restrict__ qbuf, const float* __restrict__ kvbuf,
    const float* __restrict__ rpb, float* __restrict__ att)
{
    __shared__ float qs[64 * 100];   // q, later o
    __shared__ float kvs[64 * 52];
    __shared__ float sc[16 * 384];   // [p][h*64+r]
    __shared__ float rb[294];
    const int wi = blockIdx.x;
    const int wr = wi >> 5, wc = wi & 31;
    const int t = threadIdx.x;

    for (int i = t; i < 294; i += 256) rb[i] = rpb[i];
    for (int i = t; i < 64 * 24; i += 256) {
        int r = i / 24, c4 = i % 24;
        int n = (wr * 8 + (r >> 3)) * 256 + wc * 8 + (r & 7);
        *(float4*)&qs[r * 100 + c4 * 4] = *(const float4*)&qbuf[(size_t)n * 96 + c4 * 4];
    }
    for (int i = t; i < 64 * 12; i += 256) {
        int r = i / 12, c4 = i % 12;
        int n = (wr * 8 + (r >> 3)) * 256 + wc * 8 + (r & 7);
        *(float4*)&kvs[r * 52 + c4 * 4] = *(const float4*)&kvbuf[(size_t)n * 48 + c4 * 4];
    }
    __syncthreads();

    // scores: thread (r = t>>2, g = t&3) computes p = g*4..g*4+3 for all 6 heads
    {
        const int r = t >> 2, g = t & 3;
        const int qi = r >> 4, qj = (r & 7) >> 1;
        for (int h = 0; h < 6; h++) {
            float ac0 = 0.f, ac1 = 0.f, ac2 = 0.f, ac3 = 0.f;
            #pragma unroll
            for (int d = 0; d < 16; d++) {
                int f = h * 16 + d;
                int i2 = (f >= 48) ? 1 : 0;
                int j2 = (f / 24) & 1;
                int ccc = f % 24;
                float qv = qs[r * 100 + f];
                int nb = (g * 2 + i2) * 8 + j2;
                ac0 += qv * kvs[(nb + 0) * 52 + ccc];
                ac1 += qv * kvs[(nb + 2) * 52 + ccc];
                ac2 += qv * kvs[(nb + 4) * 52 + ccc];
                ac3 += qv * kvs[(nb + 6) * 52 + ccc];
            }
            int bq = (qi - g + 3) * 7 + qj + 3;
            sc[(g * 4 + 0) * 384 + h * 64 + r] = ac0 + rb[(bq - 0) * 6 + h];
            sc[(g * 4 + 1) * 384 + h * 64 + r] = ac1 + rb[(bq - 1) * 6 + h];
            sc[(g * 4 + 2) * 384 + h * 64 + r] = ac2 + rb[(bq - 2) * 6 + h];
            sc[(g * 4 + 3) * 384 + h * 64 + r] = ac3 + rb[(bq - 3) * 6 + h];
        }
    }
    __syncthreads();

    for (int i = t; i < 384; i += 256) {
        float m = -1e30f;
        #pragma unroll
        for (int p = 0; p < 16; p++) m = fmaxf(m, sc[p * 384 + i]);
        float s = 0.f;
        #pragma unroll
        for (int p = 0; p < 16; p++) { float e = __expf(sc[p * 384 + i] - m); sc[p * 384 + i] = e; s += e; }
        float inv = 1.f / s;
        #pragma unroll
        for (int p = 0; p < 16; p++) sc[p * 384 + i] *= inv;
    }
    __syncthreads();

    // PV: thread (r = t>>2, fg = t&3) computes o[r][fg*24 .. +23]
    {
        const int r = t >> 2, fg = t & 3;
        float o[24];
        #pragma unroll
        for (int jj = 0; jj < 24; jj++) o[jj] = 0.f;
        #pragma unroll
        for (int p = 0; p < 16; p++) {
            int pi = p >> 2, pj = p & 3;
            #pragma unroll
            for (int jj = 0; jj < 24; jj++) {
                int f = fg * 24 + jj;
                int h = f >> 4;
                int i2 = (f >= 48) ? 1 : 0;
                int j2 = (f / 24) & 1;
                int ccc = f % 24;
                int nn = (pi * 2 + i2) * 8 + pj * 2 + j2;
                o[jj] += sc[p * 384 + h * 64 + r] * kvs[nn * 52 + 24 + ccc];
            }
        }
        #pragma unroll
        for (int jj = 0; jj < 24; jj++) qs[r * 100 + fg * 24 + jj] = o[jj];
    }
    __syncthreads();

    for (int i = t; i < 64 * 24; i += 256) {
        int r = i / 24, c4 = i % 24;
        int n = (wr * 8 + (r >> 3)) * 256 + wc * 8 + (r & 7);
        *(float4*)&att[(size_t)n * 96 + c4 * 4] = *(float4*)&qs[r * 100 + c4 * 4];
    }
}

__global__ void zero_kernel(float* p, int n)
{
    int i = blockIdx.x * blockDim.x + threadIdx.x;
    if (i < n) p[i] = 0.f;
}

// ---------------- SCA: K^T Q contraction over n ----------------
#define NCH 64
__global__ __launch_bounds__(256) void sca_attn_kernel(const float* __restrict__ qp,
    const float* __restrict__ kbuf, float* __restrict__ attnbuf)
{
    int blk = blockIdx.x;
    int ch = blk % NCH;
    int h  = blk / NCH;
    const float* qbase = qp   + (size_t)(h * 16) * NTOK;
    const float* kbase = kbuf + (size_t)(h * 8) * NTOK;

    float acc[8][16];
    #pragma unroll
    for (int kk = 0; kk < 8; kk++)
        #pragma unroll
        for (int qq = 0; qq < 16; qq++) acc[kk][qq] = 0.f;

    const int span = NTOK / NCH;
    int n0 = ch * span;
    for (int n = n0 + threadIdx.x; n < n0 + span; n += 256) {
        float qv[16]; float qsum = 0.f;
        #pragma unroll
        for (int d = 0; d < 16; d++) { qv[d] = qbase[(size_t)d * NTOK + n]; qsum += qv[d] * qv[d]; }
        float qinv = 1.f / fmaxf(sqrtf(qsum), 1e-12f);
        float kv[8]; float ksum = 0.f;
        #pragma unroll
        for (int d = 0; d < 8; d++) { kv[d] = kbase[(size_t)d * NTOK + n]; ksum += kv[d] * kv[d]; }
        float kinv = 1.f / fmaxf(sqrtf(ksum), 1e-12f);
        #pragma unroll
        for (int d = 0; d < 16; d++) qv[d] *= qinv;
        #pragma unroll
        for (int d = 0; d < 8; d++) kv[d] *= kinv;
        #pragma unroll
        for (int kk = 0; kk < 8; kk++)
            #pragma unroll
            for (int qq = 0; qq < 16; qq++) acc[kk][qq] += kv[kk] * qv[qq];
    }
    int lane = threadIdx.x & 63;
    #pragma unroll
    for (int kk = 0; kk < 8; kk++) {
        #pragma unroll
        for (int qq = 0; qq < 16; qq++) {
            float v = acc[kk][qq];
            #pragma unroll
            for (int off = 32; off; off >>= 1) v += __shfl_down(v, off);
            if (lane == 0) atomicAdd(&attnbuf[(h * 8 + kk) * 16 + qq], v);
        }
    }
}

__global__ void sca_softmax_kernel(float* __restrict__ attnbuf)
{
    int i = threadIdx.x;
    if (i < 48) {
        float* row = attnbuf + i * 16;
        float m = -1e30f;
        #pragma unroll
        for (int q = 0; q < 16; q++) m = fmaxf(m, row[q]);
        float s = 0.f;
        #pragma unroll
        for (int q = 0; q < 16; q++) { float e = __expf(row[q] - m); row[q] = e; s += e; }
        float inv = 1.f / s;
        #pragma unroll
        for (int q = 0; q < 16; q++) row[q] *= inv;
    }
}

#define NCH2 64
__global__ __launch_bounds__(256) void sca_out_kernel(const float* __restrict__ vbuf,
    const float* __restrict__ attnbuf, float* __restrict__ scao)
{
    int blk = blockIdx.x;
    int ch = blk % NCH2;
    int h  = blk / NCH2;
    __shared__ float at[128];
    int t = threadIdx.x;
    if (t < 128) at[t] = attnbuf[h * 128 + t];
    __syncthreads();
    const float* vbase = vbuf + (size_t)(h * 8) * NTOK;
    float*       obase = scao + (size_t)h * NTOK * 16;
    const int span = NTOK / NCH2;
    int n0 = ch * span;
    for (int n = n0 + t; n < n0 + span; n += 256) {
        float vv[8]; float vsum = 0.f;
        #pragma unroll
        for (int d = 0; d < 8; d++) { vv[d] = vbase[(size_t)d * NTOK + n]; vsum += vv[d] * vv[d]; }
        float vinv = 1.f / fmaxf(sqrtf(vsum), 1e-12f);
        #pragma unroll
        for (int q = 0; q < 16; q++) {
            float a = 0.f;
            #pragma unroll
            for (int kk = 0; kk < 8; kk++) a += vv[kk] * at[kk * 16 + q];
            obase[(size_t)n * 16 + q] = a * vinv;
        }
    }
}

// ---------------- depthwise 3x3 + bias + exact gelu * gate (64-ch chunk) ----------------
__global__ __launch_bounds__(256) void dwconv_kernel(const float* __restrict__ a,
    const float* __restrict__ g, const float* __restrict__ w,
    const float* __restrict__ bias, float* __restrict__ c, int ch0)
{
    int pix = blockIdx.x * 4 + (threadIdx.x >> 6);
    int r = pix >> 8, col = pix & 255;
    int ch = threadIdx.x & 63;
    float wv[9];
    #pragma unroll
    for (int i = 0; i < 9; i++) wv[i] = w[(ch0 + ch) * 9 + i];
    float acc = bias[ch0 + ch];
    #pragma unroll
    for (int dr = -1; dr <= 1; dr++) {
        int rr = r + dr;
        if (rr < 0 || rr > 255) continue;
        #pragma unroll
        for (int dc = -1; dc <= 1; dc++) {
            int cc = col + dc;
            if (cc < 0 || cc > 255) continue;
            acc += a[(size_t)(rr * 256 + cc) * 64 + ch] * wv[(dr + 1) * 3 + (dc + 1)];
        }
    }
    float ge = 0.5f * acc * (1.f + erff(acc * 0.70710678118f));
    c[(size_t)pix * 64 + ch] = ge * g[(size_t)pix * 64 + ch];
}

extern "C" void kernel_launch(void* const* d_in, const int* in_sizes, int n_in,
                              void* d_out, int out_size, void* d_ws, size_t ws_size,
                              hipStream_t stream)
{
    (void)in_sizes; (void)n_in; (void)out_size; (void)ws_size;
    const float* x       = (const float*)d_in[0];
    const float* n1w     = (const float*)d_in[1];
    const float* n1b     = (const float*)d_in[2];
    const float* spa_qw  = (const float*)d_in[3];
    const float* spa_qb  = (const float*)d_in[4];
    const float* spa_kvw = (const float*)d_in[5];
    const float* spa_kvb = (const float*)d_in[6];
    const float* spa_pw  = (const float*)d_in[7];
    const float* spa_pb  = (const float*)d_in[8];
    const float* rpb     = (const float*)d_in[9];
    const float* sca_qw  = (const float*)d_in[10];
    const float* sca_kvw = (const float*)d_in[11];
    const float* sca_pw  = (const float*)d_in[12];
    const float* n2w     = (const float*)d_in[13];
    const float* n2b     = (const float*)d_in[14];
    const float* fc1_w   = (const float*)d_in[15];
    const float* fc1_b   = (const float*)d_in[16];
    const float* dw_w    = (const float*)d_in[17];
    const float* dw_b    = (const float*)d_in[18];
    const float* fc2_w   = (const float*)d_in[19];
    const float* fc2_b   = (const float*)d_in[20];

    float* out = (float*)d_out;
    float* ws  = (float*)d_ws;

    const size_t NC  = (size_t)NTOK * 96;   // 6,291,456
    const size_t NKV = (size_t)NTOK * 48;   // 3,145,728
    float* R0 = ws;              // xn / xn2
    float* R1 = ws + NC;         // spa q -> att -> sca qp -> scao -> fc1 a
    float* R2 = R1 + NC;         // spa kv -> sca k -> fc1 g (spans into R3)
    float* R3 = R2 + NKV;        // sca v
    float* RA = R3 + NKV;        // sca attn (768 floats)

    const int GB = NTOK / 64;    // 1024 GEMM blocks

    for (int b = 0; b < BDIM; b++) {
        const float* xb = x   + (size_t)b * NC;
        float*       ob = out + (size_t)b * NC;

        // LN1
        ln_kernel<<<NTOK / 4, 256, 0, stream>>>(xb, n1w, n1b, R0, NTOK);

        // SPA
        gemm_kernel<6,3><<<GB, 256, 0, stream>>>(R0, spa_qw, 96, 0, 0, spa_qb, 0.25f,
                                                 nullptr, R1, 96, nullptr, 0);
        gemm_kernel<3,3><<<GB, 256, 0, stream>>>(R0, spa_kvw, 48, 0, 0, spa_kvb, 1.f,
                                                 nullptr, R2, 48, nullptr, 0);
        spa_core_kernel<<<1024, 256, 0, stream>>>(R1, R2, rpb, R1);
        gemm_kernel<6,3><<<GB, 256, 0, stream>>>(R1, spa_pw, 96, 0, 0, spa_pb, 1.f,
                                                 xb, ob, 96, nullptr, 0);

        // SCA
        gemm_kernel<6,3><<<GB, 256, 0, stream>>>(R0, sca_qw, 96, 0, 0, nullptr, 1.f,
                                                 nullptr, R1, 96, nullptr, 0);
        gemm_kernel<6,3><<<GB, 256, 0, stream>>>(R0, sca_kvw, 96, 0, 0, nullptr, 1.f,
                                                 nullptr, R2, 48, R3, 0);
        zero_kernel<<<3, 256, 0, stream>>>(RA, 768);
        sca_attn_kernel<<<6 * NCH, 256, 0, stream>>>(R1, R2, RA);
        sca_softmax_kernel<<<1, 64, 0, stream>>>(RA);
        sca_out_kernel<<<6 * NCH2, 256, 0, stream>>>(R3, RA, R1);
        gemm_kernel<6,3><<<GB, 256, 0, stream>>>(R1, sca_pw, 96, 0, 0, nullptr, 1.f,
                                                 nullptr, ob, 96, nullptr, 1);

        // FFN
        ln_kernel<<<NTOK / 4, 256, 0, stream>>>(ob, n2w, n2b, R0, NTOK);
        for (int c = 0; c < 4; c++) {
            gemm_kernel<4,3><<<GB, 256, 0, stream>>>(R0, fc1_w, 512, 0, c * 64,
                                                     fc1_b + c * 64, 1.f, nullptr, R1, 64, nullptr, 0);
            gemm_kernel<4,3><<<GB, 256, 0, stream>>>(R0, fc1_w, 512, 0, 256 + c * 64,
                                                     fc1_b + 256 + c * 64, 1.f, nullptr, R2, 64, nullptr, 0);
            dwconv_kernel<<<NTOK / 4, 256, 0, stream>>>(R1, R2, dw_w, dw_b, R2, c * 64);
            gemm_kernel<6,2><<<GB, 256, 0, stream>>>(R2, fc2_w, 96, c * 64, 0,
                                                     (c == 0) ? fc2_b : nullptr, 1.f,
                                                     nullptr, ob, 96, nullptr, c != 0 ? 1 : 1);
        }
    }
}